// Round 14
// baseline (426.926 us; speedup 1.0000x reference)
//
#include <hip/hip_runtime.h>

// XSimGCL / LightGCN propagation on MI355X.
// w = D^{-1/2} x  =>  each layer is an unweighted neighbor MEAN; no edge values.
// State = packed bf16 pairs, 128B rows.
// spmm: octet-per-row, unroll-4, DEGREE-SORTED row schedule (r14: waves get 8
// same-degree rows via rperm -> kills intra-wave max-of-8 overhang; r13 showed
// VALU 29%/HBM 40% with latency hidden => imbalance was the residual).
// Build: split-capacity buckets (r10: bucket load BIMODAL, CAPU 8192 /
// CAPI 12288), no global hist/scan; wave-shuffle scans; w0 fused into csr.
// r4: every global write is a contiguous run or full 128B lines (scattered
// partial-line stores pay ~64B HBM writeback each).

#define EMBED_DIM 64
#define NUM_LAYERS 3
#define RSHIFT 8            // 256 rows per bucket
#define RMASK 255
#define NBMAX 640           // supports N <= 163840
#define CAPU 8192           // user-bucket capacity (mean 5120)
#define CAPI 12288          // item-bucket capacity (mean 10240)
#define TP 6144             // base pairs per tile -> 2*TP staged entries
#define OUT_CAP 15360       // csr out-staging capacity (>= CAPI)

__device__ __forceinline__ int bucket_base(int b, int BSPLIT) {
    int lo = (b < BSPLIT) ? b : BSPLIT;
    int hi = (b > BSPLIT) ? (b - BSPLIT) : 0;
    return lo * CAPU + hi * CAPI;
}

// ---------------- bf16 pair helpers ----------------

__device__ __forceinline__ unsigned bf16pair(float a, float b) {
    unsigned ia = __float_as_uint(a);
    unsigned ib = __float_as_uint(b);
    ia = (ia + 0x7fffu + ((ia >> 16) & 1u)) >> 16;          // RNE, low half
    ib = (ib + 0x7fffu + ((ib >> 16) & 1u)) & 0xffff0000u;  // RNE, high half
    return ia | ib;
}
__device__ __forceinline__ float bf_lo(unsigned u) { return __uint_as_float(u << 16); }
__device__ __forceinline__ float bf_hi(unsigned u) { return __uint_as_float(u & 0xffff0000u); }

// ---------------- init: gcur[b] = bucket_base(b) ----------------

__global__ void init_gcur_kernel(int* __restrict__ gcur, int NB, int BSPLIT) {
    int b = blockIdx.x * blockDim.x + threadIdx.x;
    if (b < NB) gcur[b] = bucket_base(b, BSPLIT);
}

// ---------------- split: pairs -> 2 entries -> LDS bucket-grouped -> run copies ----------------

__global__ __launch_bounds__(256) void split_kernel(const int* __restrict__ uu,
                                                    const int* __restrict__ vv,
                                                    int* __restrict__ gcur,
                                                    int* __restrict__ bin, int E2, int NB) {
    __shared__ int h[NBMAX], exl[NBMAX], curb[NBMAX], gb[NBMAX];
    __shared__ int wp[4];
    __shared__ int stage[2 * TP];
    int tid = threadIdx.x;
    int lane = tid & 63, wid = tid >> 6;
    for (int i = tid; i < NB; i += 256) h[i] = 0;
    __syncthreads();
    int e0 = blockIdx.x * TP, e1 = min(e0 + TP, E2);
    // hist pass (int4-vectorized; e0 is 16B aligned)
    int j = e0 + tid * 4;
    for (; j + 3 < e1; j += 1024) {
        int4 u4 = *(const int4*)(uu + j);
        int4 v4 = *(const int4*)(vv + j);
        atomicAdd(&h[u4.x >> RSHIFT], 1); atomicAdd(&h[v4.x >> RSHIFT], 1);
        atomicAdd(&h[u4.y >> RSHIFT], 1); atomicAdd(&h[v4.y >> RSHIFT], 1);
        atomicAdd(&h[u4.z >> RSHIFT], 1); atomicAdd(&h[v4.z >> RSHIFT], 1);
        atomicAdd(&h[u4.w >> RSHIFT], 1); atomicAdd(&h[v4.w >> RSHIFT], 1);
    }
    for (; j < e1; ++j) {  // tail (last block only)
        atomicAdd(&h[uu[j] >> RSHIFT], 1);
        atomicAdd(&h[vv[j] >> RSHIFT], 1);
    }
    __syncthreads();
    // exclusive scan of h[0..NB) -> exl: 3 elems/thread + wave-shuffle scan
    {
        int b3 = tid * 3;
        int v0 = (b3     < NB) ? h[b3]     : 0;
        int v1 = (b3 + 1 < NB) ? h[b3 + 1] : 0;
        int v2 = (b3 + 2 < NB) ? h[b3 + 2] : 0;
        int tsum = v0 + v1 + v2;
        int x = tsum;
        for (int off = 1; off < 64; off <<= 1) {
            int y = __shfl_up(x, off, 64);
            if (lane >= off) x += y;
        }
        if (lane == 63) wp[wid] = x;
        __syncthreads();
        int wadd = 0;
        for (int k = 0; k < wid; ++k) wadd += wp[k];
        int tpre = wadd + x - tsum;
        if (b3     < NB) exl[b3]     = tpre;
        if (b3 + 1 < NB) exl[b3 + 1] = tpre + v0;
        if (b3 + 2 < NB) exl[b3 + 2] = tpre + v0 + v1;
        __syncthreads();
    }
    for (int b = tid; b < NB; b += 256) {
        curb[b] = exl[b];
        gb[b]   = h[b] ? atomicAdd(&gcur[b], h[b]) : 0;
    }
    __syncthreads();
    // scatter pass (int4-vectorized)
    j = e0 + tid * 4;
    for (; j + 3 < e1; j += 1024) {
        int4 u4 = *(const int4*)(uu + j);
        int4 v4 = *(const int4*)(vv + j);
        int p;
        p = atomicAdd(&curb[u4.x >> RSHIFT], 1); stage[p] = (v4.x << RSHIFT) | (u4.x & RMASK);
        p = atomicAdd(&curb[v4.x >> RSHIFT], 1); stage[p] = (u4.x << RSHIFT) | (v4.x & RMASK);
        p = atomicAdd(&curb[u4.y >> RSHIFT], 1); stage[p] = (v4.y << RSHIFT) | (u4.y & RMASK);
        p = atomicAdd(&curb[v4.y >> RSHIFT], 1); stage[p] = (u4.y << RSHIFT) | (v4.y & RMASK);
        p = atomicAdd(&curb[u4.z >> RSHIFT], 1); stage[p] = (v4.z << RSHIFT) | (u4.z & RMASK);
        p = atomicAdd(&curb[v4.z >> RSHIFT], 1); stage[p] = (u4.z << RSHIFT) | (v4.z & RMASK);
        p = atomicAdd(&curb[u4.w >> RSHIFT], 1); stage[p] = (v4.w << RSHIFT) | (u4.w & RMASK);
        p = atomicAdd(&curb[v4.w >> RSHIFT], 1); stage[p] = (u4.w << RSHIFT) | (v4.w & RMASK);
    }
    for (; j < e1; ++j) {
        int u = uu[j], v = vv[j];
        int p1 = atomicAdd(&curb[u >> RSHIFT], 1);
        stage[p1] = (v << RSHIFT) | (u & RMASK);
        int p2 = atomicAdd(&curb[v >> RSHIFT], 1);
        stage[p2] = (u << RSHIFT) | (v & RMASK);
    }
    __syncthreads();
    // copy runs out contiguously (one wave per bucket)
    for (int b = wid; b < NB; b += 4) {
        int cnt_b = h[b];
        int st = exl[b], g = gb[b];
        for (int k = lane; k < cnt_b; k += 64) bin[g + k] = stage[st + k];
    }
}

// ---------------- csr: per-bucket LDS counting sort + fused w0 + degree-sort perm ----------------

__global__ __launch_bounds__(256) void csr_kernel(const int* __restrict__ bin,
                                                  const int* __restrict__ gcur,
                                                  int* __restrict__ row_ptr,
                                                  int* __restrict__ deg,
                                                  int* __restrict__ col_idx,
                                                  int* __restrict__ rperm,
                                                  const float2* __restrict__ ue,
                                                  const float2* __restrict__ ie,
                                                  unsigned* __restrict__ w0x,
                                                  int N, int U, int BSPLIT) {
    __shared__ int h2[256], cur2[256];
    __shared__ float rs2[256];
    __shared__ int wp[4];
    __shared__ int dh[256], dcur[256];
    __shared__ __align__(16) int outst[OUT_CAP];
    int b   = blockIdx.x;
    int tid = threadIdx.x;
    int lane = tid & 63, wid = tid >> 6;
    int s = bucket_base(b, BSPLIT);
    int e = gcur[b];          // == s + bucket count (after split)
    int cnt = e - s;
    h2[tid] = 0;
    __syncthreads();
    // hist pass (int4; s is 16B aligned)
    int cnt4 = cnt >> 2;
    const int4* bin4 = (const int4*)(bin + s);
    for (int j = tid; j < cnt4; j += 256) {
        int4 v = bin4[j];
        atomicAdd(&h2[v.x & RMASK], 1);
        atomicAdd(&h2[v.y & RMASK], 1);
        atomicAdd(&h2[v.z & RMASK], 1);
        atomicAdd(&h2[v.w & RMASK], 1);
    }
    for (int j = (cnt4 << 2) + tid; j < cnt; j += 256) atomicAdd(&h2[bin[s + j] & RMASK], 1);
    __syncthreads();
    int myh = h2[tid];
    rs2[tid] = (myh > 0) ? rsqrtf((float)myh) : 0.0f;
    // exclusive scan of h2 via wave shuffles
    {
        int x = myh;
        for (int off = 1; off < 64; off <<= 1) {
            int y = __shfl_up(x, off, 64);
            if (lane >= off) x += y;
        }
        if (lane == 63) wp[wid] = x;
        __syncthreads();
        int wadd = 0;
        for (int k = 0; k < wid; ++k) wadd += wp[k];
        cur2[tid] = wadd + x - myh;   // exclusive
    }
    int gr = (b << RSHIFT) + tid;
    bool valid = (gr < N);
    if (valid) {
        row_ptr[gr] = s + cur2[tid];
        deg[gr]     = myh;
    }
    // degree-sort permutation: counting sort of this bucket's rows by degree
    rperm[(b << RSHIFT) + tid] = -1;          // init all 256 slots
    dh[tid] = 0;
    __syncthreads();
    int dbin = min(myh, 255);
    if (valid) atomicAdd(&dh[dbin], 1);
    __syncthreads();
    {
        int dv = dh[tid];
        int x = dv;
        for (int off = 1; off < 64; off <<= 1) {
            int y = __shfl_up(x, off, 64);
            if (lane >= off) x += y;
        }
        if (lane == 63) wp[wid] = x;
        __syncthreads();
        int wadd = 0;
        for (int k = 0; k < wid; ++k) wadd += wp[k];
        dcur[tid] = wadd + x - dv;   // exclusive
    }
    __syncthreads();
    if (valid) {
        int rk = atomicAdd(&dcur[dbin], 1);
        rperm[(b << RSHIFT) + rk] = gr;
    }
    __syncthreads();
    // placement pass
    if (cnt <= OUT_CAP) {
        for (int j = tid; j < cnt4; j += 256) {
            int4 v = bin4[j];
            int p;
            p = atomicAdd(&cur2[v.x & RMASK], 1); outst[p] = v.x >> RSHIFT;
            p = atomicAdd(&cur2[v.y & RMASK], 1); outst[p] = v.y >> RSHIFT;
            p = atomicAdd(&cur2[v.z & RMASK], 1); outst[p] = v.z >> RSHIFT;
            p = atomicAdd(&cur2[v.w & RMASK], 1); outst[p] = v.w >> RSHIFT;
        }
        for (int j = (cnt4 << 2) + tid; j < cnt; j += 256) {
            int v = bin[s + j];
            int p = atomicAdd(&cur2[v & RMASK], 1);
            outst[p] = v >> RSHIFT;
        }
        __syncthreads();
        int4* dst4 = (int4*)(col_idx + s);
        for (int j = tid; j < cnt4; j += 256) dst4[j] = ((const int4*)outst)[j];
        for (int j = (cnt4 << 2) + tid; j < cnt; j += 256) col_idx[s + j] = outst[j];
    } else {  // safety fallback
        for (int j = tid; j < cnt; j += 256) {
            int v = bin[s + j];
            int p = atomicAdd(&cur2[v & RMASK], 1);
            col_idx[s + p] = v >> RSHIFT;
        }
    }
    // fused w0: pack bf16(D^{-1/2} * emb) for this bucket's 256 rows
    for (int idx = tid; idx < 256 * 32; idx += 256) {
        int rl = idx >> 5, sub = idx & 31;
        int n = (b << RSHIFT) + rl;
        if (n < N) {
            float2 v = (n < U) ? ue[(size_t)n * 32 + sub] : ie[(size_t)(n - U) * 32 + sub];
            float rs = rs2[rl];
            w0x[(size_t)n * 32 + sub] = bf16pair(v.x * rs, v.y * rs);
        }
    }
}

// ---------------- SpMM: neighbor mean, octet-per-row, degree-sorted schedule ----------------

__global__ __launch_bounds__(256) void spmm_kernel(const int* __restrict__ rperm,
                                                   const int* __restrict__ row_ptr,
                                                   const int* __restrict__ deg,
                                                   const int* __restrict__ col_idx,
                                                   const uint4* __restrict__ x4,
                                                   uint4* __restrict__ y4, int NS) {
    int t    = blockIdx.x * blockDim.x + threadIdx.x;
    int slot = t >> 3;
    int sub  = t & 7;
    if (slot >= NS) return;
    int r = rperm[slot];
    if (r < 0) return;
    int s = row_ptr[r];
    int d = deg[r];
    float2 a0 = {0, 0}, a1 = {0, 0}, a2 = {0, 0}, a3 = {0, 0};
    int k = 0;
    for (; k + 3 < d; k += 4) {
        int c0 = col_idx[s + k];
        int c1 = col_idx[s + k + 1];
        int c2 = col_idx[s + k + 2];
        int c3 = col_idx[s + k + 3];
        uint4 u0 = x4[(size_t)c0 * 8 + sub];
        uint4 u1 = x4[(size_t)c1 * 8 + sub];
        uint4 u2 = x4[(size_t)c2 * 8 + sub];
        uint4 u3 = x4[(size_t)c3 * 8 + sub];
        a0.x += bf_lo(u0.x); a0.y += bf_hi(u0.x);
        a1.x += bf_lo(u0.y); a1.y += bf_hi(u0.y);
        a2.x += bf_lo(u0.z); a2.y += bf_hi(u0.z);
        a3.x += bf_lo(u0.w); a3.y += bf_hi(u0.w);
        a0.x += bf_lo(u1.x); a0.y += bf_hi(u1.x);
        a1.x += bf_lo(u1.y); a1.y += bf_hi(u1.y);
        a2.x += bf_lo(u1.z); a2.y += bf_hi(u1.z);
        a3.x += bf_lo(u1.w); a3.y += bf_hi(u1.w);
        a0.x += bf_lo(u2.x); a0.y += bf_hi(u2.x);
        a1.x += bf_lo(u2.y); a1.y += bf_hi(u2.y);
        a2.x += bf_lo(u2.z); a2.y += bf_hi(u2.z);
        a3.x += bf_lo(u2.w); a3.y += bf_hi(u2.w);
        a0.x += bf_lo(u3.x); a0.y += bf_hi(u3.x);
        a1.x += bf_lo(u3.y); a1.y += bf_hi(u3.y);
        a2.x += bf_lo(u3.z); a2.y += bf_hi(u3.z);
        a3.x += bf_lo(u3.w); a3.y += bf_hi(u3.w);
    }
    for (; k < d; ++k) {
        int c0 = col_idx[s + k];
        uint4 u0 = x4[(size_t)c0 * 8 + sub];
        a0.x += bf_lo(u0.x); a0.y += bf_hi(u0.x);
        a1.x += bf_lo(u0.y); a1.y += bf_hi(u0.y);
        a2.x += bf_lo(u0.z); a2.y += bf_hi(u0.z);
        a3.x += bf_lo(u0.w); a3.y += bf_hi(u0.w);
    }
    float inv = (d > 0) ? (1.0f / (float)d) : 0.0f;
    uint4 o;
    o.x = bf16pair(a0.x * inv, a0.y * inv);
    o.y = bf16pair(a1.x * inv, a1.y * inv);
    o.z = bf16pair(a2.x * inv, a2.y * inv);
    o.w = bf16pair(a3.x * inv, a3.y * inv);
    y4[(size_t)r * 8 + sub] = o;   // full 128B line per row: no write amplification
}

// ---------------- fused readout ----------------

__global__ __launch_bounds__(256) void readout_kernel(const unsigned* __restrict__ l1,
                                                      const unsigned* __restrict__ l2,
                                                      const unsigned* __restrict__ l3,
                                                      const int* __restrict__ deg,
                                                      const int* __restrict__ user_ids,
                                                      const int* __restrict__ item_ids,
                                                      float* __restrict__ out, int B, int U) {
    int b    = (blockIdx.x * blockDim.x + threadIdx.x) >> 6;
    int lane = threadIdx.x & 63;
    if (b >= B) return;
    int half = lane >> 5, sub = lane & 31;
    int row = half ? (item_ids[b] + U) : user_ids[b];
    size_t idx = (size_t)row * 32 + sub;
    unsigned u1 = l1[idx], u2 = l2[idx], u3 = l3[idx];
    float sx = bf_lo(u1) + bf_lo(u2) + bf_lo(u3);
    float sy = bf_hi(u1) + bf_hi(u2) + bf_hi(u3);
    float ox = __shfl_xor(sx, 32, 64);
    float oy = __shfl_xor(sy, 32, 64);
    float p = sx * ox + sy * oy;   // lanes 0-31: user*item partial dot
#pragma unroll
    for (int off = 16; off > 0; off >>= 1) p += __shfl_down(p, off, 64);
    if (lane == 0) {
        float du = (float)deg[user_ids[b]];
        float di = (float)deg[item_ids[b] + U];
        out[b] = p * sqrtf(du) * sqrtf(di) * (1.0f / (NUM_LAYERS * NUM_LAYERS));
    }
}

// ---------------- launch ----------------

extern "C" void kernel_launch(void* const* d_in, const int* in_sizes, int n_in,
                              void* d_out, int out_size, void* d_ws, size_t ws_size,
                              hipStream_t stream) {
    const float* user_emb = (const float*)d_in[0];
    const float* item_emb = (const float*)d_in[1];
    // d_in[2] (vals) unused: reconstructed algebraically from degrees
    const int*   rows     = (const int*)d_in[3];
    const int*   cols     = (const int*)d_in[4];
    const int*   user_ids = (const int*)d_in[5];
    const int*   item_ids = (const int*)d_in[6];
    float*       out      = (float*)d_out;

    const int U = in_sizes[0] / EMBED_DIM;
    const int I = in_sizes[1] / EMBED_DIM;
    const int E2 = in_sizes[3] >> 1;    // base pairs: rows=[u;v'], cols=[v';u]
    const int B = in_sizes[5];
    const int N = U + I;
    const int NB = (N + RMASK) >> RSHIFT;   // 256-row buckets
    const int NS = NB << RSHIFT;            // perm slots
    const int BSPLIT = U >> RSHIFT;         // buckets below: pure users

    // total bin entries = bucket_base(NB)
    const long long TOT = (long long)((NB < BSPLIT ? NB : BSPLIT)) * CAPU +
                          (long long)((NB > BSPLIT) ? (NB - BSPLIT) : 0) * CAPI;

    // workspace layout (~105MB)
    char* w = (char*)d_ws;
    unsigned* x2      = (unsigned*)w; w += (size_t)N * 32 * sizeof(unsigned);   // w0, later L3
    unsigned* L1      = (unsigned*)w; w += (size_t)N * 32 * sizeof(unsigned);
    unsigned* L2      = (unsigned*)w; w += (size_t)N * 32 * sizeof(unsigned);
    int*      bin     = (int*)w;      w += (size_t)TOT * sizeof(int);
    int*      col_idx = (int*)w;      w += (size_t)TOT * sizeof(int);
    int*      row_ptr = (int*)w;      w += (size_t)N * sizeof(int);
    int*      deg     = (int*)w;      w += (size_t)N * sizeof(int);
    int*      rperm   = (int*)w;      w += (size_t)NS * sizeof(int);
    int*      gcur    = (int*)w;      w += (size_t)NB * sizeof(int);

    const int T = 256;
    const int GP = (E2 + TP - 1) / TP;

    // CSR build: split-capacity buckets, LDS-staged counting sort, fused w0 + degree-sort
    init_gcur_kernel<<<(NB + T - 1) / T, T, 0, stream>>>(gcur, NB, BSPLIT);
    split_kernel<<<GP, T, 0, stream>>>(rows, cols, gcur, bin, E2, NB);
    csr_kernel<<<NB, T, 0, stream>>>(bin, gcur, row_ptr, deg, col_idx, rperm,
                                     (const float2*)user_emb, (const float2*)item_emb,
                                     x2, N, U, BSPLIT);

    // 3 propagation layers (neighbor mean); layer 3 reuses x2 as output
    const int GS = (NS * 8 + T - 1) / T;   // one octet (8 threads) per perm slot
    spmm_kernel<<<GS, T, 0, stream>>>(rperm, row_ptr, deg, col_idx,
                                      (const uint4*)x2, (uint4*)L1, NS);
    spmm_kernel<<<GS, T, 0, stream>>>(rperm, row_ptr, deg, col_idx,
                                      (const uint4*)L1, (uint4*)L2, NS);
    spmm_kernel<<<GS, T, 0, stream>>>(rperm, row_ptr, deg, col_idx,
                                      (const uint4*)L2, (uint4*)x2, NS);

    readout_kernel<<<(B * 64 + T - 1) / T, T, 0, stream>>>(L1, L2, x2, deg,
                                                           user_ids, item_ids, out, B, U);
}

// Round 15
// 359.559 us; speedup vs baseline: 1.1874x; 1.1874x over previous
//
#include <hip/hip_runtime.h>

// XSimGCL / LightGCN propagation on MI355X.
// w = D^{-1/2} x  =>  each layer is an unweighted neighbor MEAN; no edge values.
// State = packed bf16 pairs, 128B rows.
// spmm: octet-per-row on ADJACENT rows, unroll-4 (r13 config = best).
// r14 lesson: degree-sorted scheduling REGRESSED (adjacency loss -> +16MB L2
// fill); spmm is L2-fill-BW bound at ~2.9TB/s with a structural floor of
// ~183MB/layer (each XCD fills ~all of x + col_idx). 64us/layer ~= floor.
// r15: build-phase occupancy — split TP 6144->3072 (LDS 60->34KB, 4 blk/CU),
// octet-granular run copies (8-lane runs, was 64-lane), csr OUT_CAP 12288
// (LDS 63->51KB, 3 blk/CU).
// Build: split-capacity buckets (r10: bucket load BIMODAL, CAPU 8192 /
// CAPI 12288), no global hist/scan; wave-shuffle scans; w0 fused into csr.
// r4: every global write is a contiguous run or full 128B lines.

#define EMBED_DIM 64
#define NUM_LAYERS 3
#define RSHIFT 8            // 256 rows per bucket
#define RMASK 255
#define NBMAX 640           // supports N <= 163840
#define CAPU 8192           // user-bucket capacity (mean 5120)
#define CAPI 12288          // item-bucket capacity (mean 10240)
#define TP 3072             // base pairs per tile -> 2*TP staged entries
#define OUT_CAP 12288       // csr out-staging capacity (>= worst bucket)

__device__ __forceinline__ int bucket_base(int b, int BSPLIT) {
    int lo = (b < BSPLIT) ? b : BSPLIT;
    int hi = (b > BSPLIT) ? (b - BSPLIT) : 0;
    return lo * CAPU + hi * CAPI;
}

// ---------------- bf16 pair helpers ----------------

__device__ __forceinline__ unsigned bf16pair(float a, float b) {
    unsigned ia = __float_as_uint(a);
    unsigned ib = __float_as_uint(b);
    ia = (ia + 0x7fffu + ((ia >> 16) & 1u)) >> 16;          // RNE, low half
    ib = (ib + 0x7fffu + ((ib >> 16) & 1u)) & 0xffff0000u;  // RNE, high half
    return ia | ib;
}
__device__ __forceinline__ float bf_lo(unsigned u) { return __uint_as_float(u << 16); }
__device__ __forceinline__ float bf_hi(unsigned u) { return __uint_as_float(u & 0xffff0000u); }

// ---------------- init: gcur[b] = bucket_base(b) ----------------

__global__ void init_gcur_kernel(int* __restrict__ gcur, int NB, int BSPLIT) {
    int b = blockIdx.x * blockDim.x + threadIdx.x;
    if (b < NB) gcur[b] = bucket_base(b, BSPLIT);
}

// ---------------- split: pairs -> 2 entries -> LDS bucket-grouped -> run copies ----------------

__global__ __launch_bounds__(256) void split_kernel(const int* __restrict__ uu,
                                                    const int* __restrict__ vv,
                                                    int* __restrict__ gcur,
                                                    int* __restrict__ bin, int E2, int NB) {
    __shared__ int h[NBMAX], exl[NBMAX], curb[NBMAX], gb[NBMAX];
    __shared__ int wp[4];
    __shared__ int stage[2 * TP];
    int tid = threadIdx.x;
    int lane = tid & 63, wid = tid >> 6;
    for (int i = tid; i < NB; i += 256) h[i] = 0;
    __syncthreads();
    int e0 = blockIdx.x * TP, e1 = min(e0 + TP, E2);
    // hist pass (int4-vectorized; e0 is 16B aligned)
    int j = e0 + tid * 4;
    for (; j + 3 < e1; j += 1024) {
        int4 u4 = *(const int4*)(uu + j);
        int4 v4 = *(const int4*)(vv + j);
        atomicAdd(&h[u4.x >> RSHIFT], 1); atomicAdd(&h[v4.x >> RSHIFT], 1);
        atomicAdd(&h[u4.y >> RSHIFT], 1); atomicAdd(&h[v4.y >> RSHIFT], 1);
        atomicAdd(&h[u4.z >> RSHIFT], 1); atomicAdd(&h[v4.z >> RSHIFT], 1);
        atomicAdd(&h[u4.w >> RSHIFT], 1); atomicAdd(&h[v4.w >> RSHIFT], 1);
    }
    for (; j < e1; ++j) {  // tail (last block only)
        atomicAdd(&h[uu[j] >> RSHIFT], 1);
        atomicAdd(&h[vv[j] >> RSHIFT], 1);
    }
    __syncthreads();
    // exclusive scan of h[0..NB) -> exl: 3 elems/thread + wave-shuffle scan
    {
        int b3 = tid * 3;
        int v0 = (b3     < NB) ? h[b3]     : 0;
        int v1 = (b3 + 1 < NB) ? h[b3 + 1] : 0;
        int v2 = (b3 + 2 < NB) ? h[b3 + 2] : 0;
        int tsum = v0 + v1 + v2;
        int x = tsum;
        for (int off = 1; off < 64; off <<= 1) {
            int y = __shfl_up(x, off, 64);
            if (lane >= off) x += y;
        }
        if (lane == 63) wp[wid] = x;
        __syncthreads();
        int wadd = 0;
        for (int k = 0; k < wid; ++k) wadd += wp[k];
        int tpre = wadd + x - tsum;
        if (b3     < NB) exl[b3]     = tpre;
        if (b3 + 1 < NB) exl[b3 + 1] = tpre + v0;
        if (b3 + 2 < NB) exl[b3 + 2] = tpre + v0 + v1;
        __syncthreads();
    }
    for (int b = tid; b < NB; b += 256) {
        curb[b] = exl[b];
        gb[b]   = h[b] ? atomicAdd(&gcur[b], h[b]) : 0;
    }
    __syncthreads();
    // scatter pass (int4-vectorized)
    j = e0 + tid * 4;
    for (; j + 3 < e1; j += 1024) {
        int4 u4 = *(const int4*)(uu + j);
        int4 v4 = *(const int4*)(vv + j);
        int p;
        p = atomicAdd(&curb[u4.x >> RSHIFT], 1); stage[p] = (v4.x << RSHIFT) | (u4.x & RMASK);
        p = atomicAdd(&curb[v4.x >> RSHIFT], 1); stage[p] = (u4.x << RSHIFT) | (v4.x & RMASK);
        p = atomicAdd(&curb[u4.y >> RSHIFT], 1); stage[p] = (v4.y << RSHIFT) | (u4.y & RMASK);
        p = atomicAdd(&curb[v4.y >> RSHIFT], 1); stage[p] = (u4.y << RSHIFT) | (v4.y & RMASK);
        p = atomicAdd(&curb[u4.z >> RSHIFT], 1); stage[p] = (v4.z << RSHIFT) | (u4.z & RMASK);
        p = atomicAdd(&curb[v4.z >> RSHIFT], 1); stage[p] = (u4.z << RSHIFT) | (v4.z & RMASK);
        p = atomicAdd(&curb[u4.w >> RSHIFT], 1); stage[p] = (v4.w << RSHIFT) | (u4.w & RMASK);
        p = atomicAdd(&curb[v4.w >> RSHIFT], 1); stage[p] = (u4.w << RSHIFT) | (v4.w & RMASK);
    }
    for (; j < e1; ++j) {
        int u = uu[j], v = vv[j];
        int p1 = atomicAdd(&curb[u >> RSHIFT], 1);
        stage[p1] = (v << RSHIFT) | (u & RMASK);
        int p2 = atomicAdd(&curb[v >> RSHIFT], 1);
        stage[p2] = (u << RSHIFT) | (v & RMASK);
    }
    __syncthreads();
    // copy runs out contiguously — one OCTET per bucket run (runs avg ~10)
    int noct = tid >> 3, osub = tid & 7;
    for (int b = noct; b < NB; b += 32) {
        int cnt_b = h[b];
        int st = exl[b], g = gb[b];
        for (int k = osub; k < cnt_b; k += 8) bin[g + k] = stage[st + k];
    }
}

// ---------------- csr: per-bucket LDS counting sort + fused w0 ----------------

__global__ __launch_bounds__(256) void csr_kernel(const int* __restrict__ bin,
                                                  const int* __restrict__ gcur,
                                                  int* __restrict__ row_ptr,
                                                  int* __restrict__ deg,
                                                  int* __restrict__ col_idx,
                                                  const float2* __restrict__ ue,
                                                  const float2* __restrict__ ie,
                                                  unsigned* __restrict__ w0x,
                                                  int N, int U, int BSPLIT) {
    __shared__ int h2[256], cur2[256];
    __shared__ float rs2[256];
    __shared__ int wp[4];
    __shared__ __align__(16) int outst[OUT_CAP];
    int b   = blockIdx.x;
    int tid = threadIdx.x;
    int lane = tid & 63, wid = tid >> 6;
    int s = bucket_base(b, BSPLIT);
    int e = gcur[b];          // == s + bucket count (after split)
    int cnt = e - s;
    h2[tid] = 0;
    __syncthreads();
    // hist pass (int4; s is 16B aligned)
    int cnt4 = cnt >> 2;
    const int4* bin4 = (const int4*)(bin + s);
    for (int j = tid; j < cnt4; j += 256) {
        int4 v = bin4[j];
        atomicAdd(&h2[v.x & RMASK], 1);
        atomicAdd(&h2[v.y & RMASK], 1);
        atomicAdd(&h2[v.z & RMASK], 1);
        atomicAdd(&h2[v.w & RMASK], 1);
    }
    for (int j = (cnt4 << 2) + tid; j < cnt; j += 256) atomicAdd(&h2[bin[s + j] & RMASK], 1);
    __syncthreads();
    int myh = h2[tid];
    rs2[tid] = (myh > 0) ? rsqrtf((float)myh) : 0.0f;
    // exclusive scan of h2 via wave shuffles
    {
        int x = myh;
        for (int off = 1; off < 64; off <<= 1) {
            int y = __shfl_up(x, off, 64);
            if (lane >= off) x += y;
        }
        if (lane == 63) wp[wid] = x;
        __syncthreads();
        int wadd = 0;
        for (int k = 0; k < wid; ++k) wadd += wp[k];
        cur2[tid] = wadd + x - myh;   // exclusive
    }
    int gr = (b << RSHIFT) + tid;
    if (gr < N) {
        row_ptr[gr] = s + cur2[tid];
        deg[gr]     = myh;
    }
    __syncthreads();
    // placement pass
    if (cnt <= OUT_CAP) {
        for (int j = tid; j < cnt4; j += 256) {
            int4 v = bin4[j];
            int p;
            p = atomicAdd(&cur2[v.x & RMASK], 1); outst[p] = v.x >> RSHIFT;
            p = atomicAdd(&cur2[v.y & RMASK], 1); outst[p] = v.y >> RSHIFT;
            p = atomicAdd(&cur2[v.z & RMASK], 1); outst[p] = v.z >> RSHIFT;
            p = atomicAdd(&cur2[v.w & RMASK], 1); outst[p] = v.w >> RSHIFT;
        }
        for (int j = (cnt4 << 2) + tid; j < cnt; j += 256) {
            int v = bin[s + j];
            int p = atomicAdd(&cur2[v & RMASK], 1);
            outst[p] = v >> RSHIFT;
        }
        __syncthreads();
        int4* dst4 = (int4*)(col_idx + s);
        for (int j = tid; j < cnt4; j += 256) dst4[j] = ((const int4*)outst)[j];
        for (int j = (cnt4 << 2) + tid; j < cnt; j += 256) col_idx[s + j] = outst[j];
    } else {  // safety fallback
        for (int j = tid; j < cnt; j += 256) {
            int v = bin[s + j];
            int p = atomicAdd(&cur2[v & RMASK], 1);
            col_idx[s + p] = v >> RSHIFT;
        }
    }
    // fused w0: pack bf16(D^{-1/2} * emb) for this bucket's 256 rows
    for (int idx = tid; idx < 256 * 32; idx += 256) {
        int rl = idx >> 5, sub = idx & 31;
        int n = (b << RSHIFT) + rl;
        if (n < N) {
            float2 v = (n < U) ? ue[(size_t)n * 32 + sub] : ie[(size_t)(n - U) * 32 + sub];
            float rs = rs2[rl];
            w0x[(size_t)n * 32 + sub] = bf16pair(v.x * rs, v.y * rs);
        }
    }
}

// ---------------- SpMM: neighbor mean, octet-per-row (adjacent), unroll-4 ----------------

__global__ __launch_bounds__(256) void spmm_kernel(const int* __restrict__ row_ptr,
                                                   const int* __restrict__ deg,
                                                   const int* __restrict__ col_idx,
                                                   const uint4* __restrict__ x4,
                                                   uint4* __restrict__ y4, int N) {
    int gw   = (blockIdx.x * blockDim.x + threadIdx.x) >> 6;
    int lane = threadIdx.x & 63;
    int oct  = lane >> 3, sub = lane & 7;
    int r = gw * 8 + oct;
    if (r >= N) return;
    int s = row_ptr[r];
    int d = deg[r];
    float2 a0 = {0, 0}, a1 = {0, 0}, a2 = {0, 0}, a3 = {0, 0};
    int k = 0;
    for (; k + 3 < d; k += 4) {
        int c0 = col_idx[s + k];
        int c1 = col_idx[s + k + 1];
        int c2 = col_idx[s + k + 2];
        int c3 = col_idx[s + k + 3];
        uint4 u0 = x4[(size_t)c0 * 8 + sub];
        uint4 u1 = x4[(size_t)c1 * 8 + sub];
        uint4 u2 = x4[(size_t)c2 * 8 + sub];
        uint4 u3 = x4[(size_t)c3 * 8 + sub];
        a0.x += bf_lo(u0.x); a0.y += bf_hi(u0.x);
        a1.x += bf_lo(u0.y); a1.y += bf_hi(u0.y);
        a2.x += bf_lo(u0.z); a2.y += bf_hi(u0.z);
        a3.x += bf_lo(u0.w); a3.y += bf_hi(u0.w);
        a0.x += bf_lo(u1.x); a0.y += bf_hi(u1.x);
        a1.x += bf_lo(u1.y); a1.y += bf_hi(u1.y);
        a2.x += bf_lo(u1.z); a2.y += bf_hi(u1.z);
        a3.x += bf_lo(u1.w); a3.y += bf_hi(u1.w);
        a0.x += bf_lo(u2.x); a0.y += bf_hi(u2.x);
        a1.x += bf_lo(u2.y); a1.y += bf_hi(u2.y);
        a2.x += bf_lo(u2.z); a2.y += bf_hi(u2.z);
        a3.x += bf_lo(u2.w); a3.y += bf_hi(u2.w);
        a0.x += bf_lo(u3.x); a0.y += bf_hi(u3.x);
        a1.x += bf_lo(u3.y); a1.y += bf_hi(u3.y);
        a2.x += bf_lo(u3.z); a2.y += bf_hi(u3.z);
        a3.x += bf_lo(u3.w); a3.y += bf_hi(u3.w);
    }
    for (; k < d; ++k) {
        int c0 = col_idx[s + k];
        uint4 u0 = x4[(size_t)c0 * 8 + sub];
        a0.x += bf_lo(u0.x); a0.y += bf_hi(u0.x);
        a1.x += bf_lo(u0.y); a1.y += bf_hi(u0.y);
        a2.x += bf_lo(u0.z); a2.y += bf_hi(u0.z);
        a3.x += bf_lo(u0.w); a3.y += bf_hi(u0.w);
    }
    float inv = (d > 0) ? (1.0f / (float)d) : 0.0f;
    uint4 o;
    o.x = bf16pair(a0.x * inv, a0.y * inv);
    o.y = bf16pair(a1.x * inv, a1.y * inv);
    o.z = bf16pair(a2.x * inv, a2.y * inv);
    o.w = bf16pair(a3.x * inv, a3.y * inv);
    y4[(size_t)r * 8 + sub] = o;
}

// ---------------- fused readout ----------------

__global__ __launch_bounds__(256) void readout_kernel(const unsigned* __restrict__ l1,
                                                      const unsigned* __restrict__ l2,
                                                      const unsigned* __restrict__ l3,
                                                      const int* __restrict__ deg,
                                                      const int* __restrict__ user_ids,
                                                      const int* __restrict__ item_ids,
                                                      float* __restrict__ out, int B, int U) {
    int b    = (blockIdx.x * blockDim.x + threadIdx.x) >> 6;
    int lane = threadIdx.x & 63;
    if (b >= B) return;
    int half = lane >> 5, sub = lane & 31;
    int row = half ? (item_ids[b] + U) : user_ids[b];
    size_t idx = (size_t)row * 32 + sub;
    unsigned u1 = l1[idx], u2 = l2[idx], u3 = l3[idx];
    float sx = bf_lo(u1) + bf_lo(u2) + bf_lo(u3);
    float sy = bf_hi(u1) + bf_hi(u2) + bf_hi(u3);
    float ox = __shfl_xor(sx, 32, 64);
    float oy = __shfl_xor(sy, 32, 64);
    float p = sx * ox + sy * oy;   // lanes 0-31: user*item partial dot
#pragma unroll
    for (int off = 16; off > 0; off >>= 1) p += __shfl_down(p, off, 64);
    if (lane == 0) {
        float du = (float)deg[user_ids[b]];
        float di = (float)deg[item_ids[b] + U];
        out[b] = p * sqrtf(du) * sqrtf(di) * (1.0f / (NUM_LAYERS * NUM_LAYERS));
    }
}

// ---------------- launch ----------------

extern "C" void kernel_launch(void* const* d_in, const int* in_sizes, int n_in,
                              void* d_out, int out_size, void* d_ws, size_t ws_size,
                              hipStream_t stream) {
    const float* user_emb = (const float*)d_in[0];
    const float* item_emb = (const float*)d_in[1];
    // d_in[2] (vals) unused: reconstructed algebraically from degrees
    const int*   rows     = (const int*)d_in[3];
    const int*   cols     = (const int*)d_in[4];
    const int*   user_ids = (const int*)d_in[5];
    const int*   item_ids = (const int*)d_in[6];
    float*       out      = (float*)d_out;

    const int U = in_sizes[0] / EMBED_DIM;
    const int I = in_sizes[1] / EMBED_DIM;
    const int E2 = in_sizes[3] >> 1;    // base pairs: rows=[u;v'], cols=[v';u]
    const int B = in_sizes[5];
    const int N = U + I;
    const int NB = (N + RMASK) >> RSHIFT;   // 256-row buckets
    const int BSPLIT = U >> RSHIFT;         // buckets below: pure users

    // total bin entries = bucket_base(NB)
    const long long TOT = (long long)((NB < BSPLIT ? NB : BSPLIT)) * CAPU +
                          (long long)((NB > BSPLIT) ? (NB - BSPLIT) : 0) * CAPI;

    // workspace layout (~104MB)
    char* w = (char*)d_ws;
    unsigned* x2      = (unsigned*)w; w += (size_t)N * 32 * sizeof(unsigned);   // w0, later L3
    unsigned* L1      = (unsigned*)w; w += (size_t)N * 32 * sizeof(unsigned);
    unsigned* L2      = (unsigned*)w; w += (size_t)N * 32 * sizeof(unsigned);
    int*      bin     = (int*)w;      w += (size_t)TOT * sizeof(int);
    int*      col_idx = (int*)w;      w += (size_t)TOT * sizeof(int);
    int*      row_ptr = (int*)w;      w += (size_t)N * sizeof(int);
    int*      deg     = (int*)w;      w += (size_t)N * sizeof(int);
    int*      gcur    = (int*)w;      w += (size_t)NB * sizeof(int);

    const int T = 256;
    const int GP = (E2 + TP - 1) / TP;

    // CSR build: split-capacity buckets, LDS-staged counting sort, fused w0
    init_gcur_kernel<<<(NB + T - 1) / T, T, 0, stream>>>(gcur, NB, BSPLIT);
    split_kernel<<<GP, T, 0, stream>>>(rows, cols, gcur, bin, E2, NB);
    csr_kernel<<<NB, T, 0, stream>>>(bin, gcur, row_ptr, deg, col_idx,
                                     (const float2*)user_emb, (const float2*)item_emb,
                                     x2, N, U, BSPLIT);

    // 3 propagation layers (neighbor mean); layer 3 reuses x2 as output
    const int GS = (N * 8 + T - 1) / T;   // one octet (8 threads) per row
    spmm_kernel<<<GS, T, 0, stream>>>(row_ptr, deg, col_idx,
                                      (const uint4*)x2, (uint4*)L1, N);
    spmm_kernel<<<GS, T, 0, stream>>>(row_ptr, deg, col_idx,
                                      (const uint4*)L1, (uint4*)L2, N);
    spmm_kernel<<<GS, T, 0, stream>>>(row_ptr, deg, col_idx,
                                      (const uint4*)L2, (uint4*)x2, N);

    readout_kernel<<<(B * 64 + T - 1) / T, T, 0, stream>>>(L1, L2, x2, deg,
                                                           user_ids, item_ids, out, B, U);
}